// Round 1
// baseline (56.429 us; speedup 1.0000x reference)
//
#include <hip/hip_runtime.h>

// LDPC "belief propagation" — structural shortcut.
//
// The reference's check-node messages are always 2*atan(exp(y)) ∈ (0, pi],
// and y >= -0.5 is guaranteed (s >= 0, |v2c| <= 1 even in float arithmetic),
// so every c2v entry is >= 2*atan(exp(-0.5)) ~= 1.08 after iteration 1.
// The final soft value is sign(llr) * prod(tanh(0.5*c2v)) with every factor
// in (0.49, 0.92) -> product in [~0.06, 1), strictly positive, no underflow.
// Hence sign(soft) == sign(llr) bit-exactly, for any rounding, and the
// 50-iteration BP never flips a hard-decision bit:
//     out = (llr > 0) ? 0 : 1
// (llr == 0 gives sign 0 -> soft 0 -> not > 0 -> bit 1, which the comparison
// below also produces.)

__global__ void ldpc_hard_decision_v4(const float4* __restrict__ llr4,
                                      int4* __restrict__ out4, int n4) {
    int i = blockIdx.x * blockDim.x + threadIdx.x;
    if (i < n4) {
        float4 v = llr4[i];
        int4 r;
        r.x = (v.x > 0.0f) ? 0 : 1;
        r.y = (v.y > 0.0f) ? 0 : 1;
        r.z = (v.z > 0.0f) ? 0 : 1;
        r.w = (v.w > 0.0f) ? 0 : 1;
        out4[i] = r;
    }
}

__global__ void ldpc_hard_decision_tail(const float* __restrict__ llr,
                                        int* __restrict__ out,
                                        int start, int n) {
    int i = start + blockIdx.x * blockDim.x + threadIdx.x;
    if (i < n) {
        out[i] = (llr[i] > 0.0f) ? 0 : 1;
    }
}

extern "C" void kernel_launch(void* const* d_in, const int* in_sizes, int n_in,
                              void* d_out, int out_size, void* d_ws, size_t ws_size,
                              hipStream_t stream) {
    const float* llr = (const float*)d_in[0];
    int* out = (int*)d_out;

    const int n = out_size;          // 131072 * 7 = 917504
    const int n4 = n / 4;            // 229376, exact (917504 % 4 == 0)
    const int tail_start = n4 * 4;

    if (n4 > 0) {
        const int block = 256;
        const int grid = (n4 + block - 1) / block;   // 896 blocks
        ldpc_hard_decision_v4<<<grid, block, 0, stream>>>(
            (const float4*)llr, (int4*)out, n4);
    }
    if (tail_start < n) {
        const int rem = n - tail_start;
        ldpc_hard_decision_tail<<<(rem + 255) / 256, 256, 0, stream>>>(
            llr, out, tail_start, n);
    }
}